// Round 15
// baseline (5728.706 us; speedup 1.0000x reference)
//
#include <hip/hip_runtime.h>
#include <stdint.h>

#define TT 2048
#define DD 256
#define GG 1024
#define HWORDS 8192      // one slot: 16 WGs x (32 rows x 16 cols) tagged words, BLOCKED layout
#define RING0 64         // h0 ring slots (2MB)
#define RING1 4          // h1 ring slots
#define PROW 1024        // panel row stride bytes: [in(512) | h(512)]
#define CREW 16          // WGs per layer crew (fat WGs: 16 h-cols each)

typedef __attribute__((ext_vector_type(4))) float f32x4;
typedef __attribute__((ext_vector_type(8))) short s16x8;
typedef __attribute__((ext_vector_type(4))) unsigned u32x4;

static __device__ __forceinline__ unsigned f2bf(float f) {
    union { float f; unsigned u; } v; v.f = f;
    return (v.u + 0x7fffu + ((v.u >> 16) & 1u)) >> 16;
}
static __device__ __forceinline__ float bf2f(unsigned b) {
    union { unsigned u; float f; } v; v.u = b << 16;
    return v.f;
}
static __device__ __forceinline__ float sigm(float x) {
    return 1.0f / (1.0f + __expf(-x));
}
static __device__ __forceinline__ float tanh_f(float x) {
    x = fminf(15.0f, fmaxf(-15.0f, x));
    float e = __expf(2.0f * x);
    return (e - 1.0f) / (e + 1.0f);
}

static __device__ __forceinline__ u32x4 ld16_sys(const unsigned* p) {
    u32x4 r;
    asm volatile("global_load_dwordx4 %0, %1, off sc0 sc1"
                 : "=&v"(r) : "v"(p) : "memory");
    return r;
}
static __device__ __forceinline__ u32x4 ld16(const unsigned* p) {
    u32x4 r;
    asm volatile("global_load_dwordx4 %0, %1, off"
                 : "=&v"(r) : "v"(p) : "memory");
    return r;
}
// Publish: ONE dwordx2 per thread (2 tagged words) — single vmem op keeps the
// round-12 counted-vmcnt bookkeeping unchanged; per-WG publish is a 2KB burst.
static __device__ __forceinline__ void st8_sys(unsigned* p, uint2 d) {
    asm volatile("global_store_dwordx2 %0, %1, off sc0 sc1" :: "v"(p), "v"(d) : "memory");
}

#define VW(n) do { asm volatile("s_waitcnt vmcnt(" #n ")" ::: "memory"); \
                   __builtin_amdgcn_sched_barrier(0); } while (0)
#define LBAR() do { asm volatile("s_waitcnt lgkmcnt(0)\n\ts_barrier" ::: "memory"); \
                    __builtin_amdgcn_sched_barrier(0); } while (0)

// LIVENESS PIN for async asm loads (round-11 lesson): dest regs must stay live
// until a waitcnt retires them. Place AFTER the VW that retires them.
#define KEEP8(a) asm volatile("" :: "v"(a[0]), "v"(a[1]), "v"(a[2]), "v"(a[3]), \
                                    "v"(a[4]), "v"(a[5]), "v"(a[6]), "v"(a[7]))

static __device__ __forceinline__ bool tags_ok4(const u32x4 v[8], unsigned tag) {
    unsigned d = 0;
#pragma unroll
    for (int i = 0; i < 8; ++i)
        d |= (v[i][0] ^ tag) | (v[i][1] ^ tag) | (v[i][2] ^ tag) | (v[i][3] ^ tag);
    return (d & 0xffffu) == 0;
}

// Zero BOTH rings fully every launch (tag 0 == unpublished; replay-safe).
__global__ void k_init(unsigned* __restrict__ h0, unsigned* __restrict__ h1) {
    unsigned i = blockIdx.x * 256 + threadIdx.x;   // 2048 blocks -> 524288 words
    h0[i] = 0u;
    if (i < RING1 * HWORDS) h1[i] = 0u;
}

// Two crews of 16 fat WGs (one kernel): blocks 0..15 = L0, 16..31 = L1.
// Each WG owns 16 h-cols of its layer. Slot layout: word = w*512 + gm*16 + cj.
// Round-12 protocol otherwise: ping-pong counted-vmcnt polls, KEEP8 pins,
// blocked publish (one contiguous dwordx2/thread = 2KB burst per WG).
__launch_bounds__(256, 1)
__global__ void k_scan(const float* __restrict__ x,
                       const float* __restrict__ Wi0, const float* __restrict__ Wh0,
                       const float* __restrict__ b0,
                       const float* __restrict__ Wi1, const float* __restrict__ Wh1,
                       const float* __restrict__ b1,
                       unsigned* h0w, unsigned* h1w)
{
    const int tid = threadIdx.x;
    const bool isL0 = (blockIdx.x < CREW);
    const int w = blockIdx.x & (CREW - 1);

    const float* Wi = isL0 ? Wi0 : Wi1;
    const float* Wh = isL0 ? Wh0 : Wh1;
    const float* bb = isL0 ? b0 : b1;

    __shared__ __align__(16) unsigned char Ap[32 * PROW];
    __shared__ float zbuf[4 * 32 * 18];   // [gate][row][16 cols pad 18]

    const int lane = tid & 63;
    const int wid = tid >> 6;
    const int mt = wid & 1;        // row tile (16 rows)
    const int nt = wid >> 1;       // local gate col block of 32

    // ---- weights as MFMA B-fragments: 2 sub-tiles x 16 kf (128 VGPRs) ----
    s16x8 Bf[2][16];
#pragma unroll
    for (int t = 0; t < 2; ++t) {
        const int jloc = lane & 15;
        const int lcol = nt * 32 + t * 16 + jloc;   // [0,64): [i x16 | f x16 | g x16 | o x16]
        const int gate = lcol >> 4;
        const int jj = lcol & 15;
        const int gcol = gate * 256 + w * 16 + jj;
        const int krow = (lane >> 4) * 8;
#pragma unroll
        for (int kf = 0; kf < 16; ++kf) {
            s16x8 a;
#pragma unroll
            for (int j = 0; j < 8; ++j) {
                int k = kf * 32 + krow + j;
                float wv = (k < 256) ? Wi[(size_t)k * GG + gcol] : Wh[(size_t)(k - 256) * GG + gcol];
                a[j] = (short)f2bf(wv);
            }
            Bf[t][kf] = a;
        }
    }

    // gate-update roles: thread -> (batch gm, cols gj0, gj0+1)
    const int gm = tid >> 3;
    const int gj0 = (tid & 7) * 2;
    const float bi0_ = bb[0 * 256 + w * 16 + gj0], bf0_ = bb[1 * 256 + w * 16 + gj0];
    const float bg0_ = bb[2 * 256 + w * 16 + gj0], bo0_ = bb[3 * 256 + w * 16 + gj0];
    const float bi1_ = bb[0 * 256 + w * 16 + gj0 + 1], bf1_ = bb[1 * 256 + w * 16 + gj0 + 1];
    const float bg1_ = bb[2 * 256 + w * 16 + gj0 + 1], bo1_ = bb[3 * 256 + w * 16 + gj0 + 1];

    const int cb = tid & 63;       // x staging roles
    const int rq = tid >> 6;

    // unpack decode for [16][512] slot: thread -> fixed row rp, col base cbase2 (+64B/i)
    const unsigned rp = (unsigned)((tid >> 2) & 31);
    const unsigned usw = (rp & 7u) << 4;
    const unsigned cbase2 = (unsigned)((tid >> 7) * 32 + (tid & 3) * 8);

    const unsigned arow = (unsigned)(mt * 16 + (lane & 15));
    const unsigned rb = arow * PROW;
    const unsigned asw = (arow & 7u) << 4;

    float cs0 = 0.f, cs1 = 0.f;
    long long budget = 500000;

#define UNP_STORE(A0, A1, A2, A3, BASE, I) do {                                   \
        uint2 pk_;                                                                \
        pk_.x = ((A0) >> 16) | ((A1) & 0xffff0000u);                              \
        pk_.y = ((A2) >> 16) | ((A3) & 0xffff0000u);                              \
        *(uint2*)(Ap + rp * PROW + (((BASE) + cbase2 + 64u * (unsigned)(I)) ^ usw)) = pk_; \
    } while (0)

    if (isL0) {
        // ================= LAYER-0 CREW =================
        int known = 0;
        u32x4 xr[8];
#pragma unroll
        for (int i = 0; i < 8; ++i)
            xr[i] = ld16((const unsigned*)(x + (size_t)(i * 4 + rq) * (TT * DD) + cb * 4));
        VW(0);
        u32x4 pA[8] = {}, pB[8] = {};

        for (int c = 0; c < TT; ++c) {
            VW(1);   // retire residual poll batch + xpf; keep only the publish store
            KEEP8(pA); KEEP8(pB);
            // stage x[c] -> in-region [0,512)
#pragma unroll
            for (int i = 0; i < 8; ++i) {
                unsigned row = (unsigned)(i * 4 + rq);
                uint2 pk;
                pk.x = f2bf(__uint_as_float(xr[i][0])) | (f2bf(__uint_as_float(xr[i][1])) << 16);
                pk.y = f2bf(__uint_as_float(xr[i][2])) | (f2bf(__uint_as_float(xr[i][3])) << 16);
                *(uint2*)(Ap + row * PROW + (((unsigned)(cb * 8)) ^ ((row & 7u) << 4))) = pk;
            }
            const unsigned* s0 = h0w + (size_t)(c & (RING0 - 1)) * HWORDS + tid * 4;
#pragma unroll
            for (int i = 0; i < 8; ++i) pA[i] = ld16_sys(s0 + i * 1024);
            LBAR();   // B1: x staged

            // phase A: in-half; one A-load feeds both sub-tile chains
            f32x4 ac0 = {0.f, 0.f, 0.f, 0.f};
            f32x4 ac1 = {0.f, 0.f, 0.f, 0.f};
#pragma unroll
            for (int kf = 0; kf < 8; ++kf) {
                unsigned kb = (unsigned)kf * 64u + ((unsigned)(lane >> 4)) * 16u;
                s16x8 a = *(const s16x8*)(Ap + rb + (kb ^ asw));
                ac0 = __builtin_amdgcn_mfma_f32_16x16x32_bf16(a, Bf[0][kf], ac0, 0, 0, 0);
                ac1 = __builtin_amdgcn_mfma_f32_16x16x32_bf16(a, Bf[1][kf], ac1, 0, 0, 0);
            }
#pragma unroll
            for (int i = 0; i < 8; ++i) pB[i] = ld16_sys(s0 + i * 1024);
            VW(8);    // in-flight store(<=1)+pA+pB -> retires store+pA
            bool wA = tags_ok4(pA, (unsigned)c);
            bool ok = wA;
            while (!ok) {
                if (--budget <= 0) break;
                __builtin_amdgcn_s_sleep(1);
#pragma unroll
                for (int i = 0; i < 8; ++i) pA[i] = ld16_sys(s0 + i * 1024);
                VW(8);            // retires pB
                if (tags_ok4(pB, (unsigned)c)) { ok = true; wA = false; break; }
                if (--budget <= 0) break;
                __builtin_amdgcn_s_sleep(1);
#pragma unroll
                for (int i = 0; i < 8; ++i) pB[i] = ld16_sys(s0 + i * 1024);
                VW(8);            // retires pA
                wA = tags_ok4(pA, (unsigned)c);
                ok = wA;
            }
            // select + unpack h0[c] -> h-region [512,1024)
#pragma unroll
            for (int i = 0; i < 8; ++i) {
                unsigned a0 = wA ? pA[i][0] : pB[i][0];
                unsigned a1 = wA ? pA[i][1] : pB[i][1];
                unsigned a2 = wA ? pA[i][2] : pB[i][2];
                unsigned a3 = wA ? pA[i][3] : pB[i][3];
                UNP_STORE(a0, a1, a2, a3, 512u, i);
            }
            // prefetch x[c+1] (retired at next VW(1))
            if (c + 1 < TT) {
#pragma unroll
                for (int i = 0; i < 8; ++i)
                    xr[i] = ld16((const unsigned*)(x + (size_t)(i * 4 + rq) * (TT * DD)
                                                   + (size_t)(c + 1) * DD + cb * 4));
            }
            LBAR();   // B2: h staged

            // phase B: h-half
#pragma unroll
            for (int kf = 8; kf < 16; ++kf) {
                unsigned kb = (unsigned)kf * 64u + ((unsigned)(lane >> 4)) * 16u;
                s16x8 a = *(const s16x8*)(Ap + rb + (kb ^ asw));
                ac0 = __builtin_amdgcn_mfma_f32_16x16x32_bf16(a, Bf[0][kf], ac0, 0, 0, 0);
                ac1 = __builtin_amdgcn_mfma_f32_16x16x32_bf16(a, Bf[1][kf], ac1, 0, 0, 0);
            }
#pragma unroll
            for (int t = 0; t < 2; ++t) {
                const int n = nt * 32 + t * 16 + (lane & 15);
                const int g = n >> 4, cl = n & 15;
                f32x4 av = t ? ac1 : ac0;
#pragma unroll
                for (int r = 0; r < 4; ++r)
                    zbuf[g * 576 + (mt * 16 + (lane >> 4) * 4 + r) * 18 + cl] = av[r];
            }
            LBAR();   // B3: zbuf ready

            float zi0 = zbuf[0 * 576 + gm * 18 + gj0] + bi0_;
            float zf0 = zbuf[1 * 576 + gm * 18 + gj0] + bf0_;
            float zg0 = zbuf[2 * 576 + gm * 18 + gj0] + bg0_;
            float zo0 = zbuf[3 * 576 + gm * 18 + gj0] + bo0_;
            cs0 = sigm(zf0) * cs0 + sigm(zi0) * tanh_f(zg0);
            float hv0 = sigm(zo0) * tanh_f(cs0);
            float zi1 = zbuf[0 * 576 + gm * 18 + gj0 + 1] + bi1_;
            float zf1 = zbuf[1 * 576 + gm * 18 + gj0 + 1] + bf1_;
            float zg1 = zbuf[2 * 576 + gm * 18 + gj0 + 1] + bg1_;
            float zo1 = zbuf[3 * 576 + gm * 18 + gj0 + 1] + bo1_;
            cs1 = sigm(zf1) * cs1 + sigm(zi1) * tanh_f(zg1);
            float hv1 = sigm(zo1) * tanh_f(cs1);

            // throttle (rare): h1 tags >= c-63 prove all L1 WGs consumed h0[c-63]
            int T = c - 63;
            if (T > known) {
                const unsigned* trow = h1w + (size_t)(T & (RING1 - 1)) * HWORDS
                                     + (size_t)(lane & 15) * 512;
                for (;;) {
                    u32x4 tv = ld16_sys(trow);
                    VW(0);
                    int m = (int)(tv[0] & 0xffffu);
                    m = min(m, (int)(tv[1] & 0xffffu));
                    m = min(m, (int)(tv[2] & 0xffffu));
                    m = min(m, (int)(tv[3] & 0xffffu));
#pragma unroll
                    for (int off = 32; off; off >>= 1) m = min(m, __shfl_xor(m, off, 64));
                    if (m >= T) { known = m; break; }
                    if (--budget <= 0) break;
                    __builtin_amdgcn_s_sleep(4);
                }
            }
            uint2 pub;
            pub.x = (f2bf(hv0) << 16) | (unsigned)(c + 1);
            pub.y = (f2bf(hv1) << 16) | (unsigned)(c + 1);
            st8_sys(h0w + (size_t)((c + 1) & (RING0 - 1)) * HWORDS + w * 512 + gm * 16 + gj0, pub);
        }
    } else {
        // ================= LAYER-1 CREW =================
        u32x4 ph[8], qA[8] = {}, qB[8] = {};
        {
            const unsigned* sp = h0w + (size_t)1 * HWORDS + tid * 4;
#pragma unroll
            for (int i = 0; i < 8; ++i) ph[i] = ld16_sys(sp + i * 1024);
        }
        for (int c = 0; c < TT; ++c) {
            if (c == 0) { VW(0); } else { VW(1); }   // retire residual q + ph; keep store
            KEEP8(qA); KEEP8(qB);
            const unsigned* s0 = h0w + (size_t)((c + 1) & (RING0 - 1)) * HWORDS + tid * 4;
            while (!tags_ok4(ph, (unsigned)(c + 1))) {   // feed-forward: normally hits
                if (--budget <= 0) break;
                __builtin_amdgcn_s_sleep(1);
#pragma unroll
                for (int i = 0; i < 8; ++i) ph[i] = ld16_sys(s0 + i * 1024);
                VW(0);
            }
            // unpack h0[c+1] -> in-region [0,512)
#pragma unroll
            for (int i = 0; i < 8; ++i)
                UNP_STORE(ph[i][0], ph[i][1], ph[i][2], ph[i][3], 0u, i);

            const unsigned* s1 = h1w + (size_t)(c & (RING1 - 1)) * HWORDS + tid * 4;
#pragma unroll
            for (int i = 0; i < 8; ++i) qA[i] = ld16_sys(s1 + i * 1024);
            LBAR();   // B1: in staged

            f32x4 ac0 = {0.f, 0.f, 0.f, 0.f};
            f32x4 ac1 = {0.f, 0.f, 0.f, 0.f};
#pragma unroll
            for (int kf = 0; kf < 8; ++kf) {
                unsigned kb = (unsigned)kf * 64u + ((unsigned)(lane >> 4)) * 16u;
                s16x8 a = *(const s16x8*)(Ap + rb + (kb ^ asw));
                ac0 = __builtin_amdgcn_mfma_f32_16x16x32_bf16(a, Bf[0][kf], ac0, 0, 0, 0);
                ac1 = __builtin_amdgcn_mfma_f32_16x16x32_bf16(a, Bf[1][kf], ac1, 0, 0, 0);
            }
#pragma unroll
            for (int i = 0; i < 8; ++i) qB[i] = ld16_sys(s1 + i * 1024);
            VW(8);    // retires store+qA
            bool wA = tags_ok4(qA, (unsigned)c);
            bool ok = wA;
            while (!ok) {
                if (--budget <= 0) break;
                __builtin_amdgcn_s_sleep(1);
#pragma unroll
                for (int i = 0; i < 8; ++i) qA[i] = ld16_sys(s1 + i * 1024);
                VW(8);            // retires qB
                if (tags_ok4(qB, (unsigned)c)) { ok = true; wA = false; break; }
                if (--budget <= 0) break;
                __builtin_amdgcn_s_sleep(1);
#pragma unroll
                for (int i = 0; i < 8; ++i) qB[i] = ld16_sys(s1 + i * 1024);
                VW(8);            // retires qA
                wA = tags_ok4(qA, (unsigned)c);
                ok = wA;
            }
            // select + unpack h1[c] -> h-region [512,1024)
#pragma unroll
            for (int i = 0; i < 8; ++i) {
                unsigned a0 = wA ? qA[i][0] : qB[i][0];
                unsigned a1 = wA ? qA[i][1] : qB[i][1];
                unsigned a2 = wA ? qA[i][2] : qB[i][2];
                unsigned a3 = wA ? qA[i][3] : qB[i][3];
                UNP_STORE(a0, a1, a2, a3, 512u, i);
            }
            LBAR();   // B2: h staged

#pragma unroll
            for (int kf = 8; kf < 16; ++kf) {
                unsigned kb = (unsigned)kf * 64u + ((unsigned)(lane >> 4)) * 16u;
                s16x8 a = *(const s16x8*)(Ap + rb + (kb ^ asw));
                ac0 = __builtin_amdgcn_mfma_f32_16x16x32_bf16(a, Bf[0][kf], ac0, 0, 0, 0);
                ac1 = __builtin_amdgcn_mfma_f32_16x16x32_bf16(a, Bf[1][kf], ac1, 0, 0, 0);
            }
#pragma unroll
            for (int t = 0; t < 2; ++t) {
                const int n = nt * 32 + t * 16 + (lane & 15);
                const int g = n >> 4, cl = n & 15;
                f32x4 av = t ? ac1 : ac0;
#pragma unroll
                for (int r = 0; r < 4; ++r)
                    zbuf[g * 576 + (mt * 16 + (lane >> 4) * 4 + r) * 18 + cl] = av[r];
            }
            LBAR();   // B3: zbuf ready

            float zi0 = zbuf[0 * 576 + gm * 18 + gj0] + bi0_;
            float zf0 = zbuf[1 * 576 + gm * 18 + gj0] + bf0_;
            float zg0 = zbuf[2 * 576 + gm * 18 + gj0] + bg0_;
            float zo0 = zbuf[3 * 576 + gm * 18 + gj0] + bo0_;
            cs0 = sigm(zf0) * cs0 + sigm(zi0) * tanh_f(zg0);
            float hv0 = sigm(zo0) * tanh_f(cs0);
            float zi1 = zbuf[0 * 576 + gm * 18 + gj0 + 1] + bi1_;
            float zf1 = zbuf[1 * 576 + gm * 18 + gj0 + 1] + bf1_;
            float zg1 = zbuf[2 * 576 + gm * 18 + gj0 + 1] + bg1_;
            float zo1 = zbuf[3 * 576 + gm * 18 + gj0 + 1] + bo1_;
            cs1 = sigm(zf1) * cs1 + sigm(zi1) * tanh_f(zg1);
            float hv1 = sigm(zo1) * tanh_f(cs1);

            // prefetch next h0 polls BEFORE publish (next VW(1) keeps only the store)
            if (c + 1 < TT) {
                const unsigned* sn = h0w + (size_t)((c + 2) & (RING0 - 1)) * HWORDS + tid * 4;
#pragma unroll
                for (int i = 0; i < 8; ++i) ph[i] = ld16_sys(sn + i * 1024);
            }
            uint2 pub;
            pub.x = (f2bf(hv0) << 16) | (unsigned)(c + 1);
            pub.y = (f2bf(hv1) << 16) | (unsigned)(c + 1);
            st8_sys(h1w + (size_t)((c + 1) & (RING1 - 1)) * HWORDS + w * 512 + gm * 16 + gj0, pub);
        }
    }
#undef UNP_STORE
}

// out = h1[T] @ Wd + bd; h1 ring slot TT%4 == 0, layout word = w2*512 + m*16 + cj.
__global__ void k_dense(const unsigned* __restrict__ h1last,
                        const float* __restrict__ Wd, const float* __restrict__ bd,
                        float* __restrict__ out)
{
    __shared__ float hs[256];
    const int m = blockIdx.x;
    const int o = threadIdx.x;
    hs[o] = bf2f(h1last[(o >> 4) * 512 + m * 16 + (o & 15)] >> 16);
    __syncthreads();
    float acc = bd[o];
#pragma unroll 8
    for (int k = 0; k < 256; ++k)
        acc = fmaf(hs[k], Wd[k * 256 + o], acc);
    out[m * 256 + o] = acc;
}

extern "C" void kernel_launch(void* const* d_in, const int* in_sizes, int n_in,
                              void* d_out, int out_size, void* d_ws, size_t ws_size,
                              hipStream_t stream)
{
    const float* x   = (const float*)d_in[0];
    const float* Wi0 = (const float*)d_in[1];
    const float* Wh0 = (const float*)d_in[2];
    const float* b0  = (const float*)d_in[3];
    const float* Wi1 = (const float*)d_in[4];
    const float* Wh1 = (const float*)d_in[5];
    const float* b1  = (const float*)d_in[6];
    const float* Wd  = (const float*)d_in[7];
    const float* bd  = (const float*)d_in[8];
    float* out = (float*)d_out;

    char* ws = (char*)d_ws;
    unsigned* h0w = (unsigned*)ws;                                   // 64 slots = 2 MB
    unsigned* h1w = (unsigned*)(ws + (size_t)RING0 * HWORDS * 4);    // 4 slots = 128 KB

    k_init<<<dim3(RING0 * HWORDS / 256), dim3(256), 0, stream>>>(h0w, h1w);
    k_scan<<<dim3(2 * CREW), dim3(256), 0, stream>>>(x, Wi0, Wh0, b0, Wi1, Wh1, b1, h0w, h1w);
    k_dense<<<dim3(32), dim3(256), 0, stream>>>(
        h1w + (size_t)(TT & (RING1 - 1)) * HWORDS, Wd, bd, out);
}

// Round 16
// 4667.718 us; speedup vs baseline: 1.2273x; 1.2273x over previous
//
#include <hip/hip_runtime.h>
#include <stdint.h>

#define TT 2048
#define DD 256
#define GG 1024
#define HWORDS 8192      // one slot: 32 WGs x (32 rows x 8 cols) tagged words, BLOCKED layout
#define RING0 64         // h0 ring slots (2MB)
#define RING1 4          // h1 ring slots
#define PROW 1024        // panel row stride bytes: [in(512) | h(512)]

typedef __attribute__((ext_vector_type(4))) float f32x4;
typedef __attribute__((ext_vector_type(8))) short s16x8;
typedef __attribute__((ext_vector_type(4))) unsigned u32x4;

static __device__ __forceinline__ unsigned f2bf(float f) {
    union { float f; unsigned u; } v; v.f = f;
    return (v.u + 0x7fffu + ((v.u >> 16) & 1u)) >> 16;
}
static __device__ __forceinline__ float bf2f(unsigned b) {
    union { unsigned u; float f; } v; v.u = b << 16;
    return v.f;
}
static __device__ __forceinline__ float sigm(float x) {
    return 1.0f / (1.0f + __expf(-x));
}
static __device__ __forceinline__ float tanh_f(float x) {
    x = fminf(15.0f, fmaxf(-15.0f, x));
    float e = __expf(2.0f * x);
    return (e - 1.0f) / (e + 1.0f);
}

static __device__ __forceinline__ u32x4 ld16_sys(const unsigned* p) {
    u32x4 r;
    asm volatile("global_load_dwordx4 %0, %1, off sc0 sc1"
                 : "=&v"(r) : "v"(p) : "memory");
    return r;
}
static __device__ __forceinline__ u32x4 ld16(const unsigned* p) {
    u32x4 r;
    asm volatile("global_load_dwordx4 %0, %1, off"
                 : "=&v"(r) : "v"(p) : "memory");
    return r;
}
static __device__ __forceinline__ void st4_sys(unsigned* p, unsigned d) {
    asm volatile("global_store_dword %0, %1, off sc0 sc1" :: "v"(p), "v"(d) : "memory");
}

#define VW(n) do { asm volatile("s_waitcnt vmcnt(" #n ")" ::: "memory"); \
                   __builtin_amdgcn_sched_barrier(0); } while (0)
#define LBAR() do { asm volatile("s_waitcnt lgkmcnt(0)\n\ts_barrier" ::: "memory"); \
                    __builtin_amdgcn_sched_barrier(0); } while (0)

// LIVENESS PIN for async asm loads: an inline-asm load's dest register must stay
// live until a waitcnt retires it, else the allocator reuses the physreg and the
// late writeback clobbers it (round-11 bug). Place AFTER the VW that retires them.
#define KEEP8(a) asm volatile("" :: "v"(a[0]), "v"(a[1]), "v"(a[2]), "v"(a[3]), \
                                    "v"(a[4]), "v"(a[5]), "v"(a[6]), "v"(a[7]))

static __device__ __forceinline__ bool tags_ok4(const u32x4 v[8], unsigned tag) {
    unsigned d = 0;
#pragma unroll
    for (int i = 0; i < 8; ++i)
        d |= (v[i][0] ^ tag) | (v[i][1] ^ tag) | (v[i][2] ^ tag) | (v[i][3] ^ tag);
    return (d & 0xffffu) == 0;
}

// Zero BOTH rings fully every launch (tag 0 == unpublished; replay-safe).
__global__ void k_init(unsigned* __restrict__ h0, unsigned* __restrict__ h1) {
    unsigned i = blockIdx.x * 256 + threadIdx.x;   // 2048 blocks -> 524288 words
    h0[i] = 0u;
    if (i < RING1 * HWORDS) h1[i] = 0u;
}

// Two crews of 32 WGs (one kernel): blocks 0..31 = L0, 32..63 = L1.
// BLOCKED slot layout: word = w*256 + row*8 + col  ->  publish addr = base + w*256 + tid
// (one contiguous 1KB burst per WG). Ping-pong polls: batches A/B staggered; counted
// VW(8) retires exactly the older batch at each check. Loser batches stay pinned live
// (KEEP8) until the next cadence's VW(1) retires them.
// [CONVERGED round-12 structure: rounds 13/14/15 perturbed sample-time, scope/MFMA
//  chains, and participant count — all regressed or neutral. The ~2.26us cadence is
//  the cross-XCD store->observe visibility floor for this topology.]
__launch_bounds__(256, 1)
__global__ void k_scan(const float* __restrict__ x,
                       const float* __restrict__ Wi0, const float* __restrict__ Wh0,
                       const float* __restrict__ b0,
                       const float* __restrict__ Wi1, const float* __restrict__ Wh1,
                       const float* __restrict__ b1,
                       unsigned* h0w, unsigned* h1w)
{
    const int tid = threadIdx.x;
    const bool isL0 = (blockIdx.x < 32);
    const int w = blockIdx.x & 31;

    const float* Wi = isL0 ? Wi0 : Wi1;
    const float* Wh = isL0 ? Wh0 : Wh1;
    const float* bb = isL0 ? b0 : b1;

    __shared__ __align__(16) unsigned char Ap[32 * PROW];
    __shared__ float zbuf[4 * 32 * 10];

    const int lane = tid & 63;
    const int wid = tid >> 6;
    const int mt = wid & 1;
    const int nt = wid >> 1;

    // ---- weights as MFMA B-fragments ----
    s16x8 Bf[16];
    {
        const int jloc = lane & 15;
        const int lcol = nt * 16 + jloc;          // [i0-7 f0-7 | g0-7 o0-7]
        const int gate = lcol >> 3;
        const int jj = lcol & 7;
        const int gcol = gate * 256 + w * 8 + jj;
        const int krow = (lane >> 4) * 8;
#pragma unroll
        for (int kf = 0; kf < 16; ++kf) {
            s16x8 a;
#pragma unroll
            for (int j = 0; j < 8; ++j) {
                int k = kf * 32 + krow + j;
                float wv = (k < 256) ? Wi[(size_t)k * GG + gcol] : Wh[(size_t)(k - 256) * GG + gcol];
                a[j] = (short)f2bf(wv);
            }
            Bf[kf] = a;
        }
    }

    const int gm = tid >> 3;
    const int gj = tid & 7;
    const float bi_ = bb[0 * 256 + w * 8 + gj], bf_ = bb[1 * 256 + w * 8 + gj];
    const float bg_ = bb[2 * 256 + w * 8 + gj], bo_ = bb[3 * 256 + w * 8 + gj];

    const int cb = tid & 63;       // x staging roles
    const int rq = tid >> 6;

    // blocked-layout unpack decode (constant per thread)
    const unsigned urow = (unsigned)((tid >> 1) & 31);
    const unsigned usw = (urow & 7u) << 4;

    const unsigned arow = (unsigned)(mt * 16 + (lane & 15));
    const unsigned rb = arow * PROW;
    const unsigned asw = (arow & 7u) << 4;

    float cs = 0.f;
    long long budget = 500000;

#define UNP_STORE(A0, A1, A2, A3, BASE, I) do {                                   \
        uint2 pk_;                                                                \
        pk_.x = ((A0) >> 16) | ((A1) & 0xffff0000u);                              \
        pk_.y = ((A2) >> 16) | ((A3) & 0xffff0000u);                              \
        unsigned bcol_ = (unsigned)((I) * 4 + (tid >> 6)) * 16u                   \
                       + (unsigned)(tid & 1) * 8u;                                \
        *(uint2*)(Ap + urow * PROW + (((BASE) + bcol_) ^ usw)) = pk_;             \
    } while (0)

    if (isL0) {
        // ================= LAYER-0 CREW =================
        int known = 0;
        u32x4 xr[8];
#pragma unroll
        for (int i = 0; i < 8; ++i)
            xr[i] = ld16((const unsigned*)(x + (size_t)(i * 4 + rq) * (TT * DD) + cb * 4));
        VW(0);
        u32x4 pA[8] = {}, pB[8] = {};

        for (int c = 0; c < TT; ++c) {
            VW(1);   // retire residual poll batch + xpf; keep only newest publish store
            KEEP8(pA); KEEP8(pB);   // pin in-flight loser regs through retirement
            // stage x[c] -> in-region [0,512)
#pragma unroll
            for (int i = 0; i < 8; ++i) {
                unsigned row = (unsigned)(i * 4 + rq);
                uint2 pk;
                pk.x = f2bf(__uint_as_float(xr[i][0])) | (f2bf(__uint_as_float(xr[i][1])) << 16);
                pk.y = f2bf(__uint_as_float(xr[i][2])) | (f2bf(__uint_as_float(xr[i][3])) << 16);
                *(uint2*)(Ap + row * PROW + (((unsigned)(cb * 8)) ^ ((row & 7u) << 4))) = pk;
            }
            const unsigned* s0 = h0w + (size_t)(c & (RING0 - 1)) * HWORDS + tid * 4;
#pragma unroll
            for (int i = 0; i < 8; ++i) pA[i] = ld16_sys(s0 + i * 1024);
            LBAR();   // B1: x staged

            // phase A: in-half MFMA hides pA flight
            f32x4 accA = {0.f, 0.f, 0.f, 0.f};
#pragma unroll
            for (int kf = 0; kf < 8; ++kf) {
                unsigned kb = (unsigned)kf * 64u + ((unsigned)(lane >> 4)) * 16u;
                s16x8 a = *(const s16x8*)(Ap + rb + (kb ^ asw));
                accA = __builtin_amdgcn_mfma_f32_16x16x32_bf16(a, Bf[kf], accA, 0, 0, 0);
            }
#pragma unroll
            for (int i = 0; i < 8; ++i) pB[i] = ld16_sys(s0 + i * 1024);
            VW(8);    // in-flight store(<=1)+pA+pB -> retires store+pA
            bool wA = tags_ok4(pA, (unsigned)c);
            bool ok = wA;
            while (!ok) {
                if (--budget <= 0) break;
                __builtin_amdgcn_s_sleep(1);
#pragma unroll
                for (int i = 0; i < 8; ++i) pA[i] = ld16_sys(s0 + i * 1024);
                VW(8);            // retires pB
                if (tags_ok4(pB, (unsigned)c)) { ok = true; wA = false; break; }
                if (--budget <= 0) break;
                __builtin_amdgcn_s_sleep(1);
#pragma unroll
                for (int i = 0; i < 8; ++i) pB[i] = ld16_sys(s0 + i * 1024);
                VW(8);            // retires pA
                wA = tags_ok4(pA, (unsigned)c);
                ok = wA;
            }
            // select + unpack h0[c] -> h-region [512,1024)
#pragma unroll
            for (int i = 0; i < 8; ++i) {
                unsigned a0 = wA ? pA[i][0] : pB[i][0];
                unsigned a1 = wA ? pA[i][1] : pB[i][1];
                unsigned a2 = wA ? pA[i][2] : pB[i][2];
                unsigned a3 = wA ? pA[i][3] : pB[i][3];
                UNP_STORE(a0, a1, a2, a3, 512u, i);
            }
            // prefetch x[c+1] (retired at next VW(1))
            if (c + 1 < TT) {
#pragma unroll
                for (int i = 0; i < 8; ++i)
                    xr[i] = ld16((const unsigned*)(x + (size_t)(i * 4 + rq) * (TT * DD)
                                                   + (size_t)(c + 1) * DD + cb * 4));
            }
            LBAR();   // B2: h staged

            // phase B: h-half MFMA
            f32x4 accB = {0.f, 0.f, 0.f, 0.f};
#pragma unroll
            for (int kf = 8; kf < 16; ++kf) {
                unsigned kb = (unsigned)kf * 64u + ((unsigned)(lane >> 4)) * 16u;
                s16x8 a = *(const s16x8*)(Ap + rb + (kb ^ asw));
                accB = __builtin_amdgcn_mfma_f32_16x16x32_bf16(a, Bf[kf], accB, 0, 0, 0);
            }
            {
                f32x4 acc = accA + accB;
                const int n = nt * 16 + (lane & 15);
                const int g = n >> 3, cl = n & 7;
#pragma unroll
                for (int r = 0; r < 4; ++r)
                    zbuf[g * 320 + (mt * 16 + (lane >> 4) * 4 + r) * 10 + cl] = acc[r];
            }
            LBAR();   // B3: zbuf ready

            float zi = zbuf[0 * 320 + gm * 10 + gj] + bi_;
            float zf = zbuf[1 * 320 + gm * 10 + gj] + bf_;
            float zg = zbuf[2 * 320 + gm * 10 + gj] + bg_;
            float zo = zbuf[3 * 320 + gm * 10 + gj] + bo_;
            cs = sigm(zf) * cs + sigm(zi) * tanh_f(zg);
            float h = sigm(zo) * tanh_f(cs);

            // throttle (rare: ~1 poll round per 63 cadences): h1 tags >= c-63 prove
            // all L1 WGs consumed h0[c-63] whose slot we overwrite next.
            int T = c - 63;
            if (T > known) {
                const unsigned* trow = h1w + (size_t)(T & (RING1 - 1)) * HWORDS
                                     + (size_t)(lane & 31) * 256;
                for (;;) {
                    u32x4 tv = ld16_sys(trow);
                    VW(0);
                    int m = (int)(tv[0] & 0xffffu);
                    m = min(m, (int)(tv[1] & 0xffffu));
                    m = min(m, (int)(tv[2] & 0xffffu));
                    m = min(m, (int)(tv[3] & 0xffffu));
#pragma unroll
                    for (int off = 32; off; off >>= 1) m = min(m, __shfl_xor(m, off, 64));
                    if (m >= T) { known = m; break; }
                    if (--budget <= 0) break;
                    __builtin_amdgcn_s_sleep(4);
                }
            }
            st4_sys(h0w + (size_t)((c + 1) & (RING0 - 1)) * HWORDS + w * 256 + tid,
                    (f2bf(h) << 16) | (unsigned)(c + 1));
        }
    } else {
        // ================= LAYER-1 CREW =================
        u32x4 ph[8], qA[8] = {}, qB[8] = {};
        {
            const unsigned* sp = h0w + (size_t)1 * HWORDS + tid * 4;
#pragma unroll
            for (int i = 0; i < 8; ++i) ph[i] = ld16_sys(sp + i * 1024);
        }
        for (int c = 0; c < TT; ++c) {
            if (c == 0) { VW(0); } else { VW(1); }   // retire residual q + ph; keep store
            KEEP8(qA); KEEP8(qB);   // pin in-flight loser regs through retirement
            const unsigned* s0 = h0w + (size_t)((c + 1) & (RING0 - 1)) * HWORDS + tid * 4;
            while (!tags_ok4(ph, (unsigned)(c + 1))) {   // feed-forward: normally hits
                if (--budget <= 0) break;
                __builtin_amdgcn_s_sleep(1);
#pragma unroll
                for (int i = 0; i < 8; ++i) ph[i] = ld16_sys(s0 + i * 1024);
                VW(0);
            }
            // unpack h0[c+1] -> in-region [0,512)
#pragma unroll
            for (int i = 0; i < 8; ++i)
                UNP_STORE(ph[i][0], ph[i][1], ph[i][2], ph[i][3], 0u, i);

            const unsigned* s1 = h1w + (size_t)(c & (RING1 - 1)) * HWORDS + tid * 4;
#pragma unroll
            for (int i = 0; i < 8; ++i) qA[i] = ld16_sys(s1 + i * 1024);
            LBAR();   // B1: in staged

            f32x4 accA = {0.f, 0.f, 0.f, 0.f};
#pragma unroll
            for (int kf = 0; kf < 8; ++kf) {
                unsigned kb = (unsigned)kf * 64u + ((unsigned)(lane >> 4)) * 16u;
                s16x8 a = *(const s16x8*)(Ap + rb + (kb ^ asw));
                accA = __builtin_amdgcn_mfma_f32_16x16x32_bf16(a, Bf[kf], accA, 0, 0, 0);
            }
#pragma unroll
            for (int i = 0; i < 8; ++i) qB[i] = ld16_sys(s1 + i * 1024);
            VW(8);    // retires store+qA
            bool wA = tags_ok4(qA, (unsigned)c);
            bool ok = wA;
            while (!ok) {
                if (--budget <= 0) break;
                __builtin_amdgcn_s_sleep(1);
#pragma unroll
                for (int i = 0; i < 8; ++i) qA[i] = ld16_sys(s1 + i * 1024);
                VW(8);            // retires qB
                if (tags_ok4(qB, (unsigned)c)) { ok = true; wA = false; break; }
                if (--budget <= 0) break;
                __builtin_amdgcn_s_sleep(1);
#pragma unroll
                for (int i = 0; i < 8; ++i) qB[i] = ld16_sys(s1 + i * 1024);
                VW(8);            // retires qA
                wA = tags_ok4(qA, (unsigned)c);
                ok = wA;
            }
            // select + unpack h1[c] -> h-region [512,1024)
#pragma unroll
            for (int i = 0; i < 8; ++i) {
                unsigned a0 = wA ? qA[i][0] : qB[i][0];
                unsigned a1 = wA ? qA[i][1] : qB[i][1];
                unsigned a2 = wA ? qA[i][2] : qB[i][2];
                unsigned a3 = wA ? qA[i][3] : qB[i][3];
                UNP_STORE(a0, a1, a2, a3, 512u, i);
            }
            LBAR();   // B2: h staged

            f32x4 accB = {0.f, 0.f, 0.f, 0.f};
#pragma unroll
            for (int kf = 8; kf < 16; ++kf) {
                unsigned kb = (unsigned)kf * 64u + ((unsigned)(lane >> 4)) * 16u;
                s16x8 a = *(const s16x8*)(Ap + rb + (kb ^ asw));
                accB = __builtin_amdgcn_mfma_f32_16x16x32_bf16(a, Bf[kf], accB, 0, 0, 0);
            }
            {
                f32x4 acc = accA + accB;
                const int n = nt * 16 + (lane & 15);
                const int g = n >> 3, cl = n & 7;
#pragma unroll
                for (int r = 0; r < 4; ++r)
                    zbuf[g * 320 + (mt * 16 + (lane >> 4) * 4 + r) * 10 + cl] = acc[r];
            }
            LBAR();   // B3: zbuf ready

            float zi = zbuf[0 * 320 + gm * 10 + gj] + bi_;
            float zf = zbuf[1 * 320 + gm * 10 + gj] + bf_;
            float zg = zbuf[2 * 320 + gm * 10 + gj] + bg_;
            float zo = zbuf[3 * 320 + gm * 10 + gj] + bo_;
            cs = sigm(zf) * cs + sigm(zi) * tanh_f(zg);
            float h = sigm(zo) * tanh_f(cs);

            // prefetch next h0 polls BEFORE publish (next VW(1) keeps only the store)
            if (c + 1 < TT) {
                const unsigned* sn = h0w + (size_t)((c + 2) & (RING0 - 1)) * HWORDS + tid * 4;
#pragma unroll
                for (int i = 0; i < 8; ++i) ph[i] = ld16_sys(sn + i * 1024);
            }
            st4_sys(h1w + (size_t)((c + 1) & (RING1 - 1)) * HWORDS + w * 256 + tid,
                    (f2bf(h) << 16) | (unsigned)(c + 1));
        }
    }
#undef UNP_STORE
}

// out = h1[T] @ Wd + bd; h1 ring slot TT%4 == 0 holds blocked tagged words.
__global__ void k_dense(const unsigned* __restrict__ h1last,
                        const float* __restrict__ Wd, const float* __restrict__ bd,
                        float* __restrict__ out)
{
    __shared__ float hs[256];
    const int m = blockIdx.x;
    const int o = threadIdx.x;
    hs[o] = bf2f(h1last[(o >> 3) * 256 + m * 8 + (o & 7)] >> 16);
    __syncthreads();
    float acc = bd[o];
#pragma unroll 8
    for (int k = 0; k < 256; ++k)
        acc = fmaf(hs[k], Wd[k * 256 + o], acc);
    out[m * 256 + o] = acc;
}

extern "C" void kernel_launch(void* const* d_in, const int* in_sizes, int n_in,
                              void* d_out, int out_size, void* d_ws, size_t ws_size,
                              hipStream_t stream)
{
    const float* x   = (const float*)d_in[0];
    const float* Wi0 = (const float*)d_in[1];
    const float* Wh0 = (const float*)d_in[2];
    const float* b0  = (const float*)d_in[3];
    const float* Wi1 = (const float*)d_in[4];
    const float* Wh1 = (const float*)d_in[5];
    const float* b1  = (const float*)d_in[6];
    const float* Wd  = (const float*)d_in[7];
    const float* bd  = (const float*)d_in[8];
    float* out = (float*)d_out;

    char* ws = (char*)d_ws;
    unsigned* h0w = (unsigned*)ws;                                   // 64 slots = 2 MB
    unsigned* h1w = (unsigned*)(ws + (size_t)RING0 * HWORDS * 4);    // 4 slots = 128 KB

    k_init<<<dim3(RING0 * HWORDS / 256), dim3(256), 0, stream>>>(h0w, h1w);
    k_scan<<<dim3(64), dim3(256), 0, stream>>>(x, Wi0, Wh0, b0, Wi1, Wh1, b1, h0w, h1w);
    k_dense<<<dim3(32), dim3(256), 0, stream>>>(
        h1w + (size_t)(TT & (RING1 - 1)) * HWORDS, Wd, bd, out);
}